// Round 5
// baseline (393.105 us; speedup 1.0000x reference)
//
#include <hip/hip_runtime.h>

typedef __attribute__((ext_vector_type(4))) float  f32x4;
typedef __attribute__((ext_vector_type(4))) short  s16x4;
typedef __attribute__((ext_vector_type(4))) int    i32x4;

#define MFMAI8(a, b, c) __builtin_amdgcn_mfma_i32_16x16x64_i8((a), (b), (c), 0, 0, 0)

__device__ __forceinline__ void gload_lds16(const void* g, void* l) {
  __builtin_amdgcn_global_load_lds((const __attribute__((address_space(1))) void*)g,
                                   (__attribute__((address_space(3))) void*)l, 16, 0, 0);
}

__device__ __forceinline__ char sgn8(float v) {
  return v > 0.f ? (char)1 : (v < 0.f ? (char)-1 : (char)0);
}

// ---------------------------------------------------------------------------
// prep_w: per-oc scale = mean|w|; sign(w) as int8.
// ---------------------------------------------------------------------------
__global__ __launch_bounds__(256) void prep_w(const float* __restrict__ w3,
                                              const float* __restrict__ wpw,
                                              char* __restrict__ w1s,
                                              char* __restrict__ w2s,
                                              float* __restrict__ scale1,
                                              float* __restrict__ scale2) {
  const int o = blockIdx.x;
  const int t = threadIdx.x;
  float s = 0.f;
  if (blockIdx.y == 0) {
    for (int u = t; u < 2304; u += 256) {
      int i = u / 9, tap = u % 9;
      float v = w3[(size_t)(o * 256 + i) * 9 + tap];
      s += fabsf(v);
      w1s[(size_t)(tap * 256 + o) * 256 + i] = sgn8(v);
    }
  } else {
    float v = wpw[o * 256 + t];
    s = fabsf(v);
    w2s[o * 256 + t] = sgn8(v);
  }
  for (int m = 1; m < 64; m <<= 1) s += __shfl_xor(s, m);
  __shared__ float red[4];
  if ((t & 63) == 0) red[t >> 6] = s;
  __syncthreads();
  if (t == 0) {
    float tot = red[0] + red[1] + red[2] + red[3];
    if (blockIdx.y == 0) scale1[o] = tot / 2304.f;
    else                 scale2[o] = tot / 256.f;
  }
}

// ---------------------------------------------------------------------------
// sign_nhwc: s1[n][h][w][c] = i8 sign(x[n][c][h][w] + b11[c])
// ---------------------------------------------------------------------------
__global__ __launch_bounds__(256) void sign_nhwc(const float* __restrict__ x,
                                                 const float* __restrict__ b11,
                                                 char* __restrict__ out) {
  __shared__ unsigned short l[56 * 128];  // [w][cpair]
  __shared__ float cB[256];
  const int h = blockIdx.x, n = blockIdx.y, t = threadIdx.x;
  cB[t] = b11[t];
  __syncthreads();
  const int wv = t & 15, cg = t >> 4;
  if (wv < 14) {
    const int w0 = wv * 4;
    const int swz = (wv & 7) << 3;
#pragma unroll 4
    for (int it = 0; it < 8; ++it) {
      int cp = it * 16 + cg;       // pair index 0..127
      int c0 = cp * 2;
      size_t i0 = (size_t)(n * 256 + c0) * 3136 + h * 56 + w0;
      f32x4 x0 = *(const f32x4*)(x + i0);
      f32x4 x1 = *(const f32x4*)(x + i0 + 3136);
      float bb0 = cB[c0], bb1 = cB[c0 + 1];
      int cs = cp ^ swz;
#pragma unroll
      for (int j = 0; j < 4; ++j) {
        unsigned short pk = (unsigned char)sgn8(x0[j] + bb0) |
                            ((unsigned short)(unsigned char)sgn8(x1[j] + bb1) << 8);
        l[(w0 + j) * 128 + cs] = pk;
      }
    }
  }
  __syncthreads();
  char* op = out + ((size_t)(n * 56 + h) * 56) * 256;
  for (int u = t; u < 56 * 16; u += 256) {
    int w2 = u >> 4, cp = u & 15;   // 16-byte chunk = 8 pairs
    *(i32x4*)(op + w2 * 256 + cp * 16) =
        *(const i32x4*)&l[w2 * 128 + ((cp * 8) ^ (((w2 >> 2) & 7) << 3))];
  }
}

// ---------------------------------------------------------------------------
// conv3x3 (i8): implicit-GEMM, 3x3 pad1. T3-minimal double-buffered pipeline:
//   phase icc: issue STAGE(icc+1 -> buf^1); ds_read/MFMA on buf; __syncthreads.
// The barrier's vmcnt(0) drain lands AFTER the MFMA cluster -> loads overlap.
// LDS = 2*(40960+36864) = 155648 B -> 1 block/CU, 4 waves, pipeline not TLP.
// ---------------------------------------------------------------------------
__global__ __launch_bounds__(256, 1) void conv3x3(const char* __restrict__ sIn,
                                                  const char* __restrict__ wSgn,
                                                  short* __restrict__ raw,
                                                  float* __restrict__ S,
                                                  float* __restrict__ SS) {
  __shared__ char lin[2][10 * 64 * 64];  // [buf][row10][col64][64 ic-bytes]
  __shared__ char lw[2][9 * 64 * 64];    // [buf][tap9][oc64][64 ic-bytes]

  int bid = (blockIdx.x & 7) * 112 + (blockIdx.x >> 3);  // XCD-chunked, bijective
  const int ot = bid & 3;
  const int g  = bid >> 2;
  const int ht = g % 7, n = g / 7;
  const int h0 = ht * 8, oc0 = ot * 64;

  const int t = threadIdx.x;
  const int lane = t & 63, wv = t >> 6;
  const int cl = lane & 15, kk = lane >> 4;
  const int kswz = (kk ^ ((cl >> 1) & 3)) << 4;  // A-read slot offset

  // zero both input buffers once (left/right halo cols persist as zero)
  {
    i32x4* pl = (i32x4*)&lin[0][0];
    for (int u = t; u < 2 * 10 * 64 * 4; u += 256) pl[u] = (i32x4){0, 0, 0, 0};
  }
  __syncthreads();  // zeros visible before first STAGE overwrites valid region

  const int pw = t >> 2, sl = t & 3;
  const int srcslot = sl ^ (((1 + pw) >> 1) & 3);

#define STAGE_3x3(icc, bi)                                                          \
  {                                                                                 \
    if (t < 224) {                                                                  \
      _Pragma("unroll")                                                             \
      for (int rr = 0; rr < 10; ++rr) {                                             \
        int h = h0 - 1 + rr;                                                        \
        char* dst = &lin[bi][(rr * 64 + 1) * 64 + t * 16];                          \
        if (h >= 0 && h < 56) {                                                     \
          const char* src = sIn +                                                   \
              ((size_t)((n * 56 + h) * 56 + pw) * 256 + (icc) * 64 + srcslot * 16); \
          gload_lds16(src, dst);                                                    \
        } else {                                                                    \
          *(i32x4*)dst = (i32x4){0, 0, 0, 0};                                       \
        }                                                                           \
      }                                                                             \
    }                                                                               \
    _Pragma("unroll")                                                               \
    for (int i = 0; i < 9; ++i) {                                                   \
      int u = i * 256 + t;                                                          \
      int tap = u >> 8, oc_e = (u >> 2) & 63;                                       \
      int wslot = (u & 3) ^ ((u >> 3) & 3);                                         \
      const char* src = wSgn +                                                      \
          ((size_t)(tap * 256 + oc0 + oc_e) * 256 + (icc) * 64 + wslot * 16);       \
      gload_lds16(src, &lw[bi][u * 16]);                                            \
    }                                                                               \
  }

  int q0[7];
#pragma unroll
  for (int nf = 0; nf < 7; ++nf) {
    int p = wv * 112 + nf * 16 + cl;
    q0[nf] = (p / 56) * 64 + (p % 56);
  }

  i32x4 acc[4][7];
#pragma unroll
  for (int m = 0; m < 4; ++m)
#pragma unroll
    for (int nf = 0; nf < 7; ++nf) acc[m][nf] = (i32x4){0, 0, 0, 0};

  STAGE_3x3(0, 0);
  __syncthreads();  // prologue drain: buf0 ready

  for (int icc = 0; icc < 4; ++icc) {
    const int cur = icc & 1;
    if (icc < 3) STAGE_3x3(icc + 1, cur ^ 1);  // issue next-phase loads FIRST

#pragma unroll
    for (int kh = 0; kh < 3; ++kh)
#pragma unroll
      for (int kw = 0; kw < 3; ++kw) {
        const int tap = kh * 3 + kw;
        i32x4 a[4];
#pragma unroll
        for (int m = 0; m < 4; ++m)
          a[m] = *(const i32x4*)(&lw[cur][(tap * 64 + m * 16 + cl) * 64 + kswz]);
#pragma unroll
        for (int nf = 0; nf < 7; ++nf) {
          int qq = q0[nf] + kw;
          int addr = (qq + kh * 64) * 64 + ((kk ^ ((qq >> 1) & 3)) << 4);
          i32x4 b = *(const i32x4*)(&lin[cur][addr]);
#pragma unroll
          for (int m = 0; m < 4; ++m) acc[m][nf] = MFMAI8(a[m], b, acc[m][nf]);
        }
      }
    __syncthreads();  // drains vmcnt(0)+lgkm AFTER compute -> next buf ready
  }

  // epilogue: int16 raw + stats
#pragma unroll
  for (int m = 0; m < 4; ++m) {
    float sm[4] = {0.f, 0.f, 0.f, 0.f}, sq[4] = {0.f, 0.f, 0.f, 0.f};
#pragma unroll
    for (int nf = 0; nf < 7; ++nf) {
      int p = wv * 112 + nf * 16 + cl;
      int h = h0 + p / 56, w = p % 56;
      size_t base = ((size_t)n * 256 + oc0 + m * 16 + kk * 4) * 3136 + h * 56 + w;
      i32x4 v = acc[m][nf];
#pragma unroll
      for (int r2 = 0; r2 < 4; ++r2) {
        raw[base + (size_t)r2 * 3136] = (short)v[r2];
        float fv = (float)v[r2];
        sm[r2] += fv;
        sq[r2] += fv * fv;
      }
    }
#pragma unroll
    for (int r2 = 0; r2 < 4; ++r2) {
      float aa = sm[r2], qq = sq[r2];
      aa += __shfl_xor(aa, 1); qq += __shfl_xor(qq, 1);
      aa += __shfl_xor(aa, 2); qq += __shfl_xor(qq, 2);
      aa += __shfl_xor(aa, 4); qq += __shfl_xor(qq, 4);
      aa += __shfl_xor(aa, 8); qq += __shfl_xor(qq, 8);
      if (cl == 0) {
        int oc = oc0 + m * 16 + kk * 4 + r2;
        atomicAdd(&S[oc], aa);
        atomicAdd(&SS[oc], qq);
      }
    }
  }
}

// ---------------------------------------------------------------------------
// conv1x1 (i8): block = 256 oc x 112 px; input read once; dbuf 4-phase pipeline.
// ---------------------------------------------------------------------------
__global__ __launch_bounds__(256, 2) void conv1x1(const char* __restrict__ sIn,
                                                  const char* __restrict__ wSgn,
                                                  short* __restrict__ raw,
                                                  float* __restrict__ S,
                                                  float* __restrict__ SS) {
  __shared__ char lin[2 * 112 * 64];  // 7168 B per buf
  __shared__ char lw[2 * 256 * 64];   // 16384 B per buf

  const int b = blockIdx.x;            // 896 = 28 * 32
  const int n = b / 28;
  const int hw0 = (b % 28) * 112;
  const size_t px0 = (size_t)n * 3136 + hw0;
  const int t = threadIdx.x, lane = t & 63, wv = t >> 6;
  const int cl = lane & 15, kk = lane >> 4;
  const int kswz = (kk ^ ((cl >> 1) & 3)) << 4;

#define STAGE_1x1(icc, bufi)                                                        \
  {                                                                                 \
    for (int u = t; u < 448; u += 256) {                                            \
      int srcslot = (u & 3) ^ ((u >> 3) & 3);                                       \
      const char* src = sIn + ((px0 + (u >> 2)) * 256 + (icc) * 64 + srcslot * 16); \
      gload_lds16(src, lin + (bufi) * 7168 + u * 16);                               \
    }                                                                               \
    _Pragma("unroll")                                                               \
    for (int i = 0; i < 4; ++i) {                                                   \
      int u = i * 256 + t;                                                          \
      int srcslot = (u & 3) ^ ((u >> 3) & 3);                                       \
      const char* src = wSgn + ((size_t)(u >> 2) * 256 + (icc) * 64 + srcslot * 16);\
      gload_lds16(src, lw + (bufi) * 16384 + u * 16);                               \
    }                                                                               \
  }

  i32x4 acc[4][7];
#pragma unroll
  for (int m = 0; m < 4; ++m)
#pragma unroll
    for (int nf = 0; nf < 7; ++nf) acc[m][nf] = (i32x4){0, 0, 0, 0};

  STAGE_1x1(0, 0);
  __syncthreads();
  for (int icc = 0; icc < 4; ++icc) {
    const int cur = icc & 1;
    if (icc < 3) STAGE_1x1(icc + 1, cur ^ 1);
    i32x4 bfr[7];
#pragma unroll
    for (int nf = 0; nf < 7; ++nf)
      bfr[nf] = *(const i32x4*)(lin + cur * 7168 + (nf * 16 + cl) * 64 + kswz);
#pragma unroll
    for (int m = 0; m < 4; ++m) {
      i32x4 a = *(const i32x4*)(lw + cur * 16384 + (wv * 64 + m * 16 + cl) * 64 + kswz);
#pragma unroll
      for (int nf = 0; nf < 7; ++nf) acc[m][nf] = MFMAI8(a, bfr[nf], acc[m][nf]);
    }
    __syncthreads();
  }

#pragma unroll
  for (int m = 0; m < 4; ++m) {
    float sm[4] = {0.f, 0.f, 0.f, 0.f}, sq[4] = {0.f, 0.f, 0.f, 0.f};
    size_t base0 = ((size_t)n * 256 + wv * 64 + m * 16 + kk * 4) * 3136 + hw0;
#pragma unroll
    for (int nf = 0; nf < 7; ++nf) {
      i32x4 v = acc[m][nf];
#pragma unroll
      for (int r2 = 0; r2 < 4; ++r2) {
        raw[base0 + (size_t)r2 * 3136 + nf * 16 + cl] = (short)v[r2];
        float fv = (float)v[r2];
        sm[r2] += fv;
        sq[r2] += fv * fv;
      }
    }
#pragma unroll
    for (int r2 = 0; r2 < 4; ++r2) {
      float aa = sm[r2], qq = sq[r2];
      aa += __shfl_xor(aa, 1); qq += __shfl_xor(qq, 1);
      aa += __shfl_xor(aa, 2); qq += __shfl_xor(qq, 2);
      aa += __shfl_xor(aa, 4); qq += __shfl_xor(qq, 4);
      aa += __shfl_xor(aa, 8); qq += __shfl_xor(qq, 8);
      if (cl == 0) {
        int oc = wv * 64 + m * 16 + kk * 4 + r2;
        atomicAdd(&S[oc], aa);
        atomicAdd(&SS[oc], qq);
      }
    }
  }
}

// ---------------------------------------------------------------------------
// bn_coef: fold stats + scale + BN affine + following bias into A*raw + B
// ---------------------------------------------------------------------------
__global__ void bn_coef(const float* __restrict__ S, const float* __restrict__ SS,
                        const float* __restrict__ scale, const float* __restrict__ g,
                        const float* __restrict__ be, const float* __restrict__ bext,
                        float* __restrict__ A, float* __restrict__ B) {
  int o = threadIdx.x;
  const float invN = 1.f / 100352.f;
  float mu_r  = S[o] * invN;
  float var_r = SS[o] * invN - mu_r * mu_r;
  float sc    = scale[o];
  float rstd  = rsqrtf(sc * sc * var_r + 1e-5f);
  A[o] = g[o] * rstd * sc;
  B[o] = be[o] - g[o] * rstd * sc * mu_r + bext[o];
}

// ---------------------------------------------------------------------------
// mid_fuse: u = prelu(x + A1*raw + B1', p1) + b13 -> t1 (d_out, NCHW f32)
//           s2 = i8 sign(u + b21) (NHWC, pair-packed LDS transpose)
// ---------------------------------------------------------------------------
__global__ __launch_bounds__(256) void mid_fuse(const short* __restrict__ raw,
                                                const float* __restrict__ x,
                                                const float* __restrict__ A1,
                                                const float* __restrict__ B1,
                                                const float* __restrict__ p1,
                                                const float* __restrict__ b13,
                                                const float* __restrict__ b21,
                                                float* __restrict__ t1,
                                                char* __restrict__ s2) {
  __shared__ unsigned short l[56 * 128];
  __shared__ float cA[256], cB[256], cP[256], cD[256], cE[256];
  const int h = blockIdx.x, n = blockIdx.y, t = threadIdx.x;
  cA[t] = A1[t]; cB[t] = B1[t]; cP[t] = p1[t]; cD[t] = b13[t]; cE[t] = b21[t];
  __syncthreads();
  const int wv = t & 15, cg = t >> 4;
  if (wv < 14) {
    const int w0 = wv * 4;
    const int swz = (wv & 7) << 3;
#pragma unroll 2
    for (int it = 0; it < 8; ++it) {
      int cp = it * 16 + cg;
      int c0 = cp * 2;
      size_t i0 = (size_t)(n * 256 + c0) * 3136 + h * 56 + w0;
      f32x4 x0 = *(const f32x4*)(x + i0);
      f32x4 x1 = *(const f32x4*)(x + i0 + 3136);
      s16x4 r0 = *(const s16x4*)(raw + i0);
      s16x4 r1 = *(const s16x4*)(raw + i0 + 3136);
      float a0 = cA[c0], b0 = cB[c0], p0 = cP[c0], d0 = cD[c0], e0 = cE[c0];
      float a1 = cA[c0+1], b1 = cB[c0+1], p1v = cP[c0+1], d1 = cD[c0+1], e1 = cE[c0+1];
      f32x4 o0, o1;
      int cs = cp ^ swz;
#pragma unroll
      for (int j = 0; j < 4; ++j) {
        float u0 = x0[j] + a0 * (float)r0[j] + b0;
        u0 = (u0 >= 0.f ? u0 : p0 * u0) + d0;
        o0[j] = u0;
        float u1 = x1[j] + a1 * (float)r1[j] + b1;
        u1 = (u1 >= 0.f ? u1 : p1v * u1) + d1;
        o1[j] = u1;
        unsigned short pk = (unsigned char)sgn8(u0 + e0) |
                            ((unsigned short)(unsigned char)sgn8(u1 + e1) << 8);
        l[(w0 + j) * 128 + cs] = pk;
      }
      *(f32x4*)(t1 + i0) = o0;
      *(f32x4*)(t1 + i0 + 3136) = o1;
    }
  }
  __syncthreads();
  char* op = s2 + ((size_t)(n * 56 + h) * 56) * 256;
  for (int u = t; u < 56 * 16; u += 256) {
    int w2 = u >> 4, cp = u & 15;
    *(i32x4*)(op + w2 * 256 + cp * 16) =
        *(const i32x4*)&l[w2 * 128 + ((cp * 8) ^ (((w2 >> 2) & 7) << 3))];
  }
}

// ---------------------------------------------------------------------------
// final_fuse: out = prelu(A2*raw + B2' + t1, p2) + b23  (block per (n,c) plane)
// ---------------------------------------------------------------------------
__global__ __launch_bounds__(256) void final_fuse(const short* __restrict__ raw,
                                                  const float* __restrict__ A2,
                                                  const float* __restrict__ B2,
                                                  const float* __restrict__ p2,
                                                  const float* __restrict__ b23,
                                                  float* out) {
  const int c = blockIdx.x & 255;
  const size_t base = (size_t)blockIdx.x * 3136;
  const float a = A2[c], b = B2[c], p = p2[c], d = b23[c];
  for (int i = threadIdx.x; i < 784; i += 256) {
    s16x4 r  = *(const s16x4*)(raw + base + (size_t)i * 4);
    f32x4 tt = *(const f32x4*)(out + base + (size_t)i * 4);
    f32x4 o;
#pragma unroll
    for (int j = 0; j < 4; ++j) {
      float v = a * (float)r[j] + b + tt[j];
      o[j] = (v >= 0.f ? v : p * v) + d;
    }
    *(f32x4*)(out + base + (size_t)i * 4) = o;
  }
}

// ---------------------------------------------------------------------------
extern "C" void kernel_launch(void* const* d_in, const int* in_sizes, int n_in,
                              void* d_out, int out_size, void* d_ws, size_t ws_size,
                              hipStream_t stream) {
  const float* x   = (const float*)d_in[0];
  const float* b11 = (const float*)d_in[1];
  const float* b12 = (const float*)d_in[2];
  const float* b13 = (const float*)d_in[3];
  const float* b21 = (const float*)d_in[4];
  const float* b22 = (const float*)d_in[5];
  const float* b23 = (const float*)d_in[6];
  const float* w3  = (const float*)d_in[7];
  const float* wpw = (const float*)d_in[8];
  const float* g1  = (const float*)d_in[9];
  const float* be1 = (const float*)d_in[10];
  const float* g2  = (const float*)d_in[11];
  const float* be2 = (const float*)d_in[12];
  const float* p1  = (const float*)d_in[13];
  const float* p2  = (const float*)d_in[14];

  char* ws = (char*)d_ws;
  short* raw    = (short*)(ws);                //  51,380,224 B
  char*  sgn    = (char*)(ws + 51380224);      //  25,690,112 B
  char*  w1s    = (char*)(ws + 77070336);      //     589,824 B
  char*  w2s    = (char*)(ws + 77660160);      //      65,536 B
  float* scale1 = (float*)(ws + 77725696);
  float* scale2 = (float*)(ws + 77726720);
  float* S1     = (float*)(ws + 77727744);
  float* SS1    = (float*)(ws + 77728768);
  float* S2     = (float*)(ws + 77729792);
  float* SS2    = (float*)(ws + 77730816);
  float* A1     = (float*)(ws + 77731840);
  float* B1     = (float*)(ws + 77732864);
  float* A2     = (float*)(ws + 77733888);
  float* B2     = (float*)(ws + 77734912);
  float* t1     = (float*)d_out;

  hipMemsetAsync(ws + 77727744, 0, 4096, stream);  // zero S1,SS1,S2,SS2

  prep_w<<<dim3(256, 2), 256, 0, stream>>>(w3, wpw, w1s, w2s, scale1, scale2);
  sign_nhwc<<<dim3(56, 32), 256, 0, stream>>>(x, b11, sgn);
  conv3x3<<<dim3(896), 256, 0, stream>>>(sgn, w1s, raw, S1, SS1);
  bn_coef<<<1, 256, 0, stream>>>(S1, SS1, scale1, g1, be1, b12, A1, B1);
  mid_fuse<<<dim3(56, 32), 256, 0, stream>>>(raw, x, A1, B1, p1, b13, b21, t1, sgn);
  conv1x1<<<dim3(896), 256, 0, stream>>>(sgn, w2s, raw, S2, SS2);
  bn_coef<<<1, 256, 0, stream>>>(S2, SS2, scale2, g2, be2, b22, A2, B2);
  final_fuse<<<dim3(8192), 256, 0, stream>>>(raw, A2, B2, p2, b23, (float*)d_out);
}